// Round 3
// baseline (473.995 us; speedup 1.0000x reference)
//
#include <hip/hip_runtime.h>
#include <math.h>

#define NROW   8000
#define NFEATD 512
#define NHID   128
#define NCLS   64
#define CAP    64
#define EPSV   1e-12f
#define ALV    0.1f
#define NTRAIN 500

typedef __attribute__((ext_vector_type(8))) short bf16x8;
typedef __attribute__((ext_vector_type(4))) float f32x4;

__device__ __forceinline__ float wsum(float v) {
#pragma unroll
  for (int off = 32; off > 0; off >>= 1) v += __shfl_xor(v, off, 64);
  return v;
}
__device__ __forceinline__ float wmax(float v) {
#pragma unroll
  for (int off = 32; off > 0; off >>= 1) v = fmaxf(v, __shfl_xor(v, off, 64));
  return v;
}
__device__ __forceinline__ unsigned short f2bf(float f) {   // RTN-even
  unsigned int u = __float_as_uint(f);
  unsigned int r = u + 0x7FFFu + ((u >> 16) & 1u);
  return (unsigned short)(r >> 16);
}

// ---------------------------------------------------------------------------
// Fused front-end, block-role partitioned. Grid 8500 x 256.
//   blockIdx % 17 == 16 : GEMM tile g = blockIdx/17 (500 tiles of 16 rows)
//                         h = relu(x @ W0 + b0) via bf16 MFMA 16x16x32,
//                         x/W0 cast to bf16 on the fly (no global xb/w0s).
//   else                 : adj row = (blockIdx/17)*16 + blockIdx%17 (8000 rows)
//                         float4 scan + wave prefix-sum compaction -> cols/nnz.
// The GEMM (~15 us of compute) hides under the memory-bound 256MB adj scan.
// ---------------------------------------------------------------------------
__global__ __launch_bounds__(256) void k_front(const float* __restrict__ adj,
                                               const float* __restrict__ x,
                                               const float* __restrict__ W0,
                                               const float* __restrict__ b0,
                                               float* __restrict__ h,
                                               int* __restrict__ cols,
                                               int* __restrict__ nnz) {
  __shared__ unsigned short bsh[5120];   // 128 cols * 40 shorts (gemm role)
  __shared__ int cnt;                    // (csr role)
  const int t = threadIdx.x;
  const int lane = t & 63;
  const int g = blockIdx.x / 17;
  const int r = blockIdx.x - g * 17;

  if (r == 16) {
    // ---------------- GEMM role ----------------
    const int w = t >> 6;
    const int m = lane & 15, q = lane >> 4;
    const int row0 = g * 16;
    const int wcol = w * 32;
    const float* ap = x + (size_t)(row0 + m) * NFEATD + q * 8;
    f32x4 acc0 = {0.f, 0.f, 0.f, 0.f}, acc1 = {0.f, 0.f, 0.f, 0.f};

    for (int c = 0; c < 16; ++c) {
      // stage B: W0[c*32+k][n] -> bf16 at bsh[n*40+k] (pad k in [32,40))
#pragma unroll
      for (int i = 0; i < 4; ++i) {
        int f = t + i * 256;               // 0..1023
        int k = f >> 5, n4 = (f & 31) << 2;
        float4 wv = *(const float4*)(W0 + (size_t)(c * 32 + k) * NHID + n4);
        bsh[(n4 + 0) * 40 + k] = f2bf(wv.x);
        bsh[(n4 + 1) * 40 + k] = f2bf(wv.y);
        bsh[(n4 + 2) * 40 + k] = f2bf(wv.z);
        bsh[(n4 + 3) * 40 + k] = f2bf(wv.w);
      }
      // A fragment: 8 f32 -> bf16x8 in-register
      float4 a0 = *(const float4*)(ap + c * 32);
      float4 a1 = *(const float4*)(ap + c * 32 + 4);
      bf16x8 av;
      av[0] = (short)f2bf(a0.x); av[1] = (short)f2bf(a0.y);
      av[2] = (short)f2bf(a0.z); av[3] = (short)f2bf(a0.w);
      av[4] = (short)f2bf(a1.x); av[5] = (short)f2bf(a1.y);
      av[6] = (short)f2bf(a1.z); av[7] = (short)f2bf(a1.w);
      __syncthreads();
      bf16x8 bv0 = *(const bf16x8*)&bsh[(wcol + m) * 40 + q * 8];
      bf16x8 bv1 = *(const bf16x8*)&bsh[(wcol + 16 + m) * 40 + q * 8];
      acc0 = __builtin_amdgcn_mfma_f32_16x16x32_bf16(av, bv0, acc0, 0, 0, 0);
      acc1 = __builtin_amdgcn_mfma_f32_16x16x32_bf16(av, bv1, acc1, 0, 0, 0);
      __syncthreads();
    }
    const float bc0 = b0[wcol + m], bc1 = b0[wcol + 16 + m];
#pragma unroll
    for (int reg = 0; reg < 4; ++reg) {
      int rr = row0 + q * 4 + reg;
      h[(size_t)rr * NHID + wcol + m] = fmaxf(acc0[reg] + bc0, 0.f);
      h[(size_t)rr * NHID + wcol + 16 + m] = fmaxf(acc1[reg] + bc1, 0.f);
    }
  } else {
    // ---------------- CSR role ----------------
    const int row = g * 16 + r;
    if (t == 0) cnt = 0;
    __syncthreads();
    const float4* rp = (const float4*)(adj + (size_t)row * NROW);
    for (int f = t; f < NROW / 4 + 255; f += 256) {   // keep all lanes in shuffles
      float4 v = {0.f, 0.f, 0.f, 0.f};
      if (f < NROW / 4) v = rp[f];
      int c4 = (v.x != 0.f) + (v.y != 0.f) + (v.z != 0.f) + (v.w != 0.f);
      int pfx = c4;                                   // inclusive prefix over wave
#pragma unroll
      for (int off = 1; off < 64; off <<= 1) {
        int tv = __shfl_up(pfx, off, 64);
        if (lane >= off) pfx += tv;
      }
      int tot = __shfl(pfx, 63, 64);
      if (tot) {
        int base = 0;
        if (lane == 63) base = atomicAdd(&cnt, tot);
        base = __shfl(base, 63, 64);
        int p = base + pfx - c4;
        if (v.x != 0.f) { if (p < CAP) cols[row * CAP + p] = f * 4 + 0; ++p; }
        if (v.y != 0.f) { if (p < CAP) cols[row * CAP + p] = f * 4 + 1; ++p; }
        if (v.z != 0.f) { if (p < CAP) cols[row * CAP + p] = f * 4 + 2; ++p; }
        if (v.w != 0.f) { if (p < CAP) cols[row * CAP + p] = f * 4 + 3; ++p; }
      }
    }
    __syncthreads();
    if (t == 0) nnz[row] = cnt > CAP ? CAP : cnt;
  }
}

// ---------------------------------------------------------------------------
// Fused: Pseudo = h@W1 + b1 (+ 0.1*count(row in idx)*y_label[row]) -> outP
// then y_hat = softmax(Pseudo). Injection count via bsearch in sorted idx.
// Grid 2000 x 256, wave per row.
// ---------------------------------------------------------------------------
__global__ __launch_bounds__(256) void k_pseudo(const float* __restrict__ h,
                                                const float* __restrict__ W1,
                                                const float* __restrict__ b1,
                                                const int* __restrict__ idx,
                                                const float* __restrict__ yl,
                                                float* __restrict__ yh,
                                                float* __restrict__ outP) {
  __shared__ float hr[4][NHID];
  __shared__ int ids[NTRAIN];
  const int w = threadIdx.x >> 6, lane = threadIdx.x & 63;
  const int row = blockIdx.x * 4 + w;
  for (int i = threadIdx.x; i < NTRAIN; i += 256) ids[i] = idx[i];
  hr[w][lane] = h[(size_t)row * NHID + lane];
  hr[w][lane + 64] = h[(size_t)row * NHID + 64 + lane];
  __syncthreads();
  float acc = b1[lane];
#pragma unroll 8
  for (int k = 0; k < NHID; ++k) acc += hr[w][k] * W1[k * NCLS + lane];
  int lo = 0, hi = NTRAIN;
  while (lo < hi) { int mid = (lo + hi) >> 1; if (ids[mid] < row) lo = mid + 1; else hi = mid; }
  int lb = lo; hi = NTRAIN;
  while (lo < hi) { int mid = (lo + hi) >> 1; if (ids[mid] <= row) lo = mid + 1; else hi = mid; }
  int count = lo - lb;
  if (count) acc += ALV * (float)count * yl[(size_t)row * NCLS + lane];
  outP[(size_t)row * NCLS + lane] = acc;
  float mx = wmax(acc);
  float e = __expf(acc - mx);
  float s = wsum(e);
  yh[(size_t)row * NCLS + lane] = e / s;
}

// ---------------------------------------------------------------------------
// Fused edge weights + propagation layer 1. Grid 2000 x 256, wave per row.
// ---------------------------------------------------------------------------
__global__ __launch_bounds__(256) void k_ewp1(const float* __restrict__ yh,
                                              const float* __restrict__ h,
                                              const int* __restrict__ cols,
                                              const int* __restrict__ nnz,
                                              float* __restrict__ wv,
                                              float* __restrict__ lib) {
  const int w = threadIdx.x >> 6, lane = threadIdx.x & 63;
  const int row = blockIdx.x * 4 + w;
  (void)w;
  const int ne = nnz[row];
  int jv = 0;
  if (lane < ne) jv = cols[row * CAP + lane];
  const float yi = yh[(size_t)row * NCLS + lane];
  float rs = 0.f, myw = 0.f;
  for (int e = 0; e < ne; ++e) {
    int j = __shfl(jv, e, 64);
    float p = wsum(yi * yh[(size_t)j * NCLS + lane]);
    if (lane == e) myw = p;
    rs += p;
  }
  myw *= 1.f / fmaxf(rs, EPSV);
  if (lane < ne) wv[row * CAP + lane] = myw;
  float a0 = 0.f, a1 = 0.f;
  for (int e = 0; e < ne; ++e) {
    int j = __shfl(jv, e, 64);
    float wt = __shfl(myw, e, 64);
    a0 += wt * h[(size_t)j * NHID + lane];
    a1 += wt * h[(size_t)j * NHID + 64 + lane];
  }
  float v0 = (1.f - ALV) * a0 + ALV * h[(size_t)row * NHID + lane];
  float v1 = (1.f - ALV) * a1 + ALV * h[(size_t)row * NHID + 64 + lane];
  float s = wsum(v0 * v0 + v1 * v1);
  float inv = 1.f / fmaxf(sqrtf(s), EPSV);
  lib[(size_t)row * NHID + lane] = v0 * inv;
  lib[(size_t)row * NHID + 64 + lane] = v1 * inv;
}

// ---------------------------------------------------------------------------
// Fused propagation layer 2 + final head. Grid 2000 x 256, wave per row.
// ---------------------------------------------------------------------------
__global__ __launch_bounds__(256) void k_p2fin(const float* __restrict__ lib,
                                               const float* __restrict__ h,
                                               const int* __restrict__ cols,
                                               const int* __restrict__ nnz,
                                               const float* __restrict__ wv,
                                               const float* __restrict__ W2,
                                               const float* __restrict__ b2,
                                               float* __restrict__ out) {
  __shared__ float lrow[4][NHID];
  const int w = threadIdx.x >> 6, lane = threadIdx.x & 63;
  const int row = blockIdx.x * 4 + w;
  const int ne = nnz[row];
  int jv = 0; float wt = 0.f;
  if (lane < ne) { jv = cols[row * CAP + lane]; wt = wv[row * CAP + lane]; }
  float a0 = 0.f, a1 = 0.f;
  for (int e = 0; e < ne; ++e) {
    int j = __shfl(jv, e, 64);
    float we = __shfl(wt, e, 64);
    a0 += we * lib[(size_t)j * NHID + lane];
    a1 += we * lib[(size_t)j * NHID + 64 + lane];
  }
  float v0 = (1.f - ALV) * a0 + ALV * h[(size_t)row * NHID + lane];
  float v1 = (1.f - ALV) * a1 + ALV * h[(size_t)row * NHID + 64 + lane];
  float s = wsum(v0 * v0 + v1 * v1);
  float inv = 1.f / fmaxf(sqrtf(s), EPSV);
  lrow[w][lane] = v0 * inv;
  lrow[w][lane + 64] = v1 * inv;
  __syncthreads();
  float acc = b2[lane];
#pragma unroll 8
  for (int k = 0; k < NHID; ++k) acc += lrow[w][k] * W2[k * NCLS + lane];
  float mx = wmax(acc);
  float l = acc - mx;
  float se = wsum(__expf(l));
  out[(size_t)row * NCLS + lane] = l - __logf(se);
}

// ---------------------------------------------------------------------------
extern "C" void kernel_launch(void* const* d_in, const int* in_sizes, int n_in,
                              void* d_out, int out_size, void* d_ws, size_t ws_size,
                              hipStream_t stream) {
  const float* x   = (const float*)d_in[0];
  const float* adj = (const float*)d_in[1];
  const float* yl  = (const float*)d_in[2];
  const int*   idx = (const int*)d_in[3];
  const float* W0  = (const float*)d_in[4];
  const float* b0  = (const float*)d_in[5];
  const float* W1  = (const float*)d_in[6];
  const float* b1  = (const float*)d_in[7];
  const float* W2  = (const float*)d_in[8];
  const float* b2  = (const float*)d_in[9];
  float* out = (float*)d_out;

  char* wsb = (char*)d_ws;
  float* h    = (float*)(wsb);                  // 4,096,000 B
  float* lib  = (float*)(wsb + 4096000);        // 4,096,000 B
  float* yh   = (float*)(wsb + 8192000);        // 2,048,000 B
  float* wv   = (float*)(wsb + 10240000);       // 2,048,000 B
  int*   cols = (int*)(wsb + 12288000);         // 2,048,000 B
  int*   nnz  = (int*)(wsb + 14336000);         //    32,000 B

  k_front <<<8500, 256, 0, stream>>>(adj, x, W0, b0, h, cols, nnz);
  k_pseudo<<<2000, 256, 0, stream>>>(h, W1, b1, idx, yl, yh, out + 512000);
  k_ewp1  <<<2000, 256, 0, stream>>>(yh, h, cols, nnz, wv, lib);
  k_p2fin <<<2000, 256, 0, stream>>>(lib, h, cols, nnz, wv, W2, b2, out);
}

// Round 4
// 466.499 us; speedup vs baseline: 1.0161x; 1.0161x over previous
//
#include <hip/hip_runtime.h>
#include <math.h>

#define NROW   8000
#define NFEATD 512
#define NHID   128
#define NCLS   64
#define CAP    64
#define EPSV   1e-12f
#define ALV    0.1f
#define NTRAIN 500

typedef __attribute__((ext_vector_type(8))) short bf16x8;
typedef __attribute__((ext_vector_type(4))) float f32x4;

__device__ __forceinline__ float wsum(float v) {
#pragma unroll
  for (int off = 32; off > 0; off >>= 1) v += __shfl_xor(v, off, 64);
  return v;
}
__device__ __forceinline__ float wmax(float v) {
#pragma unroll
  for (int off = 32; off > 0; off >>= 1) v = fmaxf(v, __shfl_xor(v, off, 64));
  return v;
}
__device__ __forceinline__ unsigned short f2bf(float f) {   // RTN-even
  unsigned int u = __float_as_uint(f);
  unsigned int r = u + 0x7FFFu + ((u >> 16) & 1u);
  return (unsigned short)(r >> 16);
}

// ---------------------------------------------------------------------------
// Fused front-end, block-role partitioned. Grid 8500 x 256.
//   blockIdx % 17 == 16 : GEMM tile (500 tiles of 16 rows): h = relu(x@W0+b0)
//                         via bf16 MFMA, casting on the fly.
//   else                 : adj row scan -> cols/nnz. BW-bound design: all 8
//                         float4 loads issued up-front (32KB/block in flight),
//                         ONE wave prefix + ONE LDS atomic per wave total.
// ---------------------------------------------------------------------------
__global__ __launch_bounds__(256) void k_front(const float* __restrict__ adj,
                                               const float* __restrict__ x,
                                               const float* __restrict__ W0,
                                               const float* __restrict__ b0,
                                               float* __restrict__ h,
                                               int* __restrict__ cols,
                                               int* __restrict__ nnz) {
  __shared__ unsigned short bsh[5120];   // 128 cols * 40 shorts (gemm role)
  __shared__ int cnt;                    // (csr role)
  const int t = threadIdx.x;
  const int lane = t & 63;
  const int g = blockIdx.x / 17;
  const int r = blockIdx.x - g * 17;

  if (r == 16) {
    // ---------------- GEMM role ----------------
    const int w = t >> 6;
    const int m = lane & 15, q = lane >> 4;
    const int row0 = g * 16;
    const int wcol = w * 32;
    const float* ap = x + (size_t)(row0 + m) * NFEATD + q * 8;
    f32x4 acc0 = {0.f, 0.f, 0.f, 0.f}, acc1 = {0.f, 0.f, 0.f, 0.f};

    for (int c = 0; c < 16; ++c) {
#pragma unroll
      for (int i = 0; i < 4; ++i) {
        int f = t + i * 256;               // 0..1023
        int k = f >> 5, n4 = (f & 31) << 2;
        float4 wv = *(const float4*)(W0 + (size_t)(c * 32 + k) * NHID + n4);
        bsh[(n4 + 0) * 40 + k] = f2bf(wv.x);
        bsh[(n4 + 1) * 40 + k] = f2bf(wv.y);
        bsh[(n4 + 2) * 40 + k] = f2bf(wv.z);
        bsh[(n4 + 3) * 40 + k] = f2bf(wv.w);
      }
      float4 a0 = *(const float4*)(ap + c * 32);
      float4 a1 = *(const float4*)(ap + c * 32 + 4);
      bf16x8 av;
      av[0] = (short)f2bf(a0.x); av[1] = (short)f2bf(a0.y);
      av[2] = (short)f2bf(a0.z); av[3] = (short)f2bf(a0.w);
      av[4] = (short)f2bf(a1.x); av[5] = (short)f2bf(a1.y);
      av[6] = (short)f2bf(a1.z); av[7] = (short)f2bf(a1.w);
      __syncthreads();
      bf16x8 bv0 = *(const bf16x8*)&bsh[(wcol + m) * 40 + q * 8];
      bf16x8 bv1 = *(const bf16x8*)&bsh[(wcol + 16 + m) * 40 + q * 8];
      acc0 = __builtin_amdgcn_mfma_f32_16x16x32_bf16(av, bv0, acc0, 0, 0, 0);
      acc1 = __builtin_amdgcn_mfma_f32_16x16x32_bf16(av, bv1, acc1, 0, 0, 0);
      __syncthreads();
    }
    const float bc0 = b0[wcol + m], bc1 = b0[wcol + 16 + m];
#pragma unroll
    for (int reg = 0; reg < 4; ++reg) {
      int rr = row0 + q * 4 + reg;
      h[(size_t)rr * NHID + wcol + m] = fmaxf(acc0[reg] + bc0, 0.f);
      h[(size_t)rr * NHID + wcol + 16 + m] = fmaxf(acc1[reg] + bc1, 0.f);
    }
  } else {
    // ---------------- CSR role (BW-bound) ----------------
    const int row = g * 16 + r;
    if (t == 0) cnt = 0;
    const float4* rp = (const float4*)(adj + (size_t)row * NROW);
    // 2000 float4s per row; thread t covers f = t + 256*i, i=0..7 (f<2000).
    float4 vv[8];
    const float4 z4 = {0.f, 0.f, 0.f, 0.f};
#pragma unroll
    for (int i = 0; i < 7; ++i) vv[i] = rp[t + (i << 8)];
    vv[7] = (t < 2000 - 1792) ? rp[t + 1792] : z4;

    int c = 0;
#pragma unroll
    for (int i = 0; i < 8; ++i)
      c += (vv[i].x != 0.f) + (vv[i].y != 0.f) + (vv[i].z != 0.f) + (vv[i].w != 0.f);

    int pfx = c;                          // inclusive prefix over the wave
#pragma unroll
    for (int off = 1; off < 64; off <<= 1) {
      int tv = __shfl_up(pfx, off, 64);
      if (lane >= off) pfx += tv;
    }
    __syncthreads();                      // cnt=0 visible
    int base = 0;
    if (lane == 63 && pfx) base = atomicAdd(&cnt, pfx);
    base = __shfl(base, 63, 64);
    int p = base + pfx - c;
    if (c) {
#pragma unroll
      for (int i = 0; i < 8; ++i) {
        int f4 = (t + (i << 8)) << 2;
        if (vv[i].x != 0.f) { if (p < CAP) cols[row * CAP + p] = f4 + 0; ++p; }
        if (vv[i].y != 0.f) { if (p < CAP) cols[row * CAP + p] = f4 + 1; ++p; }
        if (vv[i].z != 0.f) { if (p < CAP) cols[row * CAP + p] = f4 + 2; ++p; }
        if (vv[i].w != 0.f) { if (p < CAP) cols[row * CAP + p] = f4 + 3; ++p; }
      }
    }
    __syncthreads();
    if (t == 0) nnz[row] = cnt > CAP ? CAP : cnt;
  }
}

// ---------------------------------------------------------------------------
// Fused: Pseudo = h@W1 + b1 (+ 0.1*count(row in idx)*y_label[row]) -> outP
// then y_hat = softmax(Pseudo). Grid 2000 x 256, wave per row.
// ---------------------------------------------------------------------------
__global__ __launch_bounds__(256) void k_pseudo(const float* __restrict__ h,
                                                const float* __restrict__ W1,
                                                const float* __restrict__ b1,
                                                const int* __restrict__ idx,
                                                const float* __restrict__ yl,
                                                float* __restrict__ yh,
                                                float* __restrict__ outP) {
  __shared__ float hr[4][NHID];
  __shared__ int ids[NTRAIN];
  const int w = threadIdx.x >> 6, lane = threadIdx.x & 63;
  const int row = blockIdx.x * 4 + w;
  for (int i = threadIdx.x; i < NTRAIN; i += 256) ids[i] = idx[i];
  hr[w][lane] = h[(size_t)row * NHID + lane];
  hr[w][lane + 64] = h[(size_t)row * NHID + 64 + lane];
  __syncthreads();
  float acc = b1[lane];
#pragma unroll 8
  for (int k = 0; k < NHID; ++k) acc += hr[w][k] * W1[k * NCLS + lane];
  int lo = 0, hi = NTRAIN;
  while (lo < hi) { int mid = (lo + hi) >> 1; if (ids[mid] < row) lo = mid + 1; else hi = mid; }
  int lb = lo; hi = NTRAIN;
  while (lo < hi) { int mid = (lo + hi) >> 1; if (ids[mid] <= row) lo = mid + 1; else hi = mid; }
  int count = lo - lb;
  if (count) acc += ALV * (float)count * yl[(size_t)row * NCLS + lane];
  outP[(size_t)row * NCLS + lane] = acc;
  float mx = wmax(acc);
  float e = __expf(acc - mx);
  float s = wsum(e);
  yh[(size_t)row * NCLS + lane] = e / s;
}

// ---------------------------------------------------------------------------
// Fused edge weights + propagation layer 1. Grid 2000 x 256, wave per row.
// ---------------------------------------------------------------------------
__global__ __launch_bounds__(256) void k_ewp1(const float* __restrict__ yh,
                                              const float* __restrict__ h,
                                              const int* __restrict__ cols,
                                              const int* __restrict__ nnz,
                                              float* __restrict__ wv,
                                              float* __restrict__ lib) {
  const int w = threadIdx.x >> 6, lane = threadIdx.x & 63;
  const int row = blockIdx.x * 4 + w;
  (void)w;
  const int ne = nnz[row];
  int jv = 0;
  if (lane < ne) jv = cols[row * CAP + lane];
  const float yi = yh[(size_t)row * NCLS + lane];
  float rs = 0.f, myw = 0.f;
  for (int e = 0; e < ne; ++e) {
    int j = __shfl(jv, e, 64);
    float p = wsum(yi * yh[(size_t)j * NCLS + lane]);
    if (lane == e) myw = p;
    rs += p;
  }
  myw *= 1.f / fmaxf(rs, EPSV);
  if (lane < ne) wv[row * CAP + lane] = myw;
  float a0 = 0.f, a1 = 0.f;
  for (int e = 0; e < ne; ++e) {
    int j = __shfl(jv, e, 64);
    float wt = __shfl(myw, e, 64);
    a0 += wt * h[(size_t)j * NHID + lane];
    a1 += wt * h[(size_t)j * NHID + 64 + lane];
  }
  float v0 = (1.f - ALV) * a0 + ALV * h[(size_t)row * NHID + lane];
  float v1 = (1.f - ALV) * a1 + ALV * h[(size_t)row * NHID + 64 + lane];
  float s = wsum(v0 * v0 + v1 * v1);
  float inv = 1.f / fmaxf(sqrtf(s), EPSV);
  lib[(size_t)row * NHID + lane] = v0 * inv;
  lib[(size_t)row * NHID + 64 + lane] = v1 * inv;
}

// ---------------------------------------------------------------------------
// Fused propagation layer 2 + final head. Grid 2000 x 256, wave per row.
// ---------------------------------------------------------------------------
__global__ __launch_bounds__(256) void k_p2fin(const float* __restrict__ lib,
                                               const float* __restrict__ h,
                                               const int* __restrict__ cols,
                                               const int* __restrict__ nnz,
                                               const float* __restrict__ wv,
                                               const float* __restrict__ W2,
                                               const float* __restrict__ b2,
                                               float* __restrict__ out) {
  __shared__ float lrow[4][NHID];
  const int w = threadIdx.x >> 6, lane = threadIdx.x & 63;
  const int row = blockIdx.x * 4 + w;
  const int ne = nnz[row];
  int jv = 0; float wt = 0.f;
  if (lane < ne) { jv = cols[row * CAP + lane]; wt = wv[row * CAP + lane]; }
  float a0 = 0.f, a1 = 0.f;
  for (int e = 0; e < ne; ++e) {
    int j = __shfl(jv, e, 64);
    float we = __shfl(wt, e, 64);
    a0 += we * lib[(size_t)j * NHID + lane];
    a1 += we * lib[(size_t)j * NHID + 64 + lane];
  }
  float v0 = (1.f - ALV) * a0 + ALV * h[(size_t)row * NHID + lane];
  float v1 = (1.f - ALV) * a1 + ALV * h[(size_t)row * NHID + 64 + lane];
  float s = wsum(v0 * v0 + v1 * v1);
  float inv = 1.f / fmaxf(sqrtf(s), EPSV);
  lrow[w][lane] = v0 * inv;
  lrow[w][lane + 64] = v1 * inv;
  __syncthreads();
  float acc = b2[lane];
#pragma unroll 8
  for (int k = 0; k < NHID; ++k) acc += lrow[w][k] * W2[k * NCLS + lane];
  float mx = wmax(acc);
  float l = acc - mx;
  float se = wsum(__expf(l));
  out[(size_t)row * NCLS + lane] = l - __logf(se);
}

// ---------------------------------------------------------------------------
extern "C" void kernel_launch(void* const* d_in, const int* in_sizes, int n_in,
                              void* d_out, int out_size, void* d_ws, size_t ws_size,
                              hipStream_t stream) {
  const float* x   = (const float*)d_in[0];
  const float* adj = (const float*)d_in[1];
  const float* yl  = (const float*)d_in[2];
  const int*   idx = (const int*)d_in[3];
  const float* W0  = (const float*)d_in[4];
  const float* b0  = (const float*)d_in[5];
  const float* W1  = (const float*)d_in[6];
  const float* b1  = (const float*)d_in[7];
  const float* W2  = (const float*)d_in[8];
  const float* b2  = (const float*)d_in[9];
  float* out = (float*)d_out;

  char* wsb = (char*)d_ws;
  float* h    = (float*)(wsb);                  // 4,096,000 B
  float* lib  = (float*)(wsb + 4096000);        // 4,096,000 B
  float* yh   = (float*)(wsb + 8192000);        // 2,048,000 B
  float* wv   = (float*)(wsb + 10240000);       // 2,048,000 B
  int*   cols = (int*)(wsb + 12288000);         // 2,048,000 B
  int*   nnz  = (int*)(wsb + 14336000);         //    32,000 B

  k_front <<<8500, 256, 0, stream>>>(adj, x, W0, b0, h, cols, nnz);
  k_pseudo<<<2000, 256, 0, stream>>>(h, W1, b1, idx, yl, yh, out + 512000);
  k_ewp1  <<<2000, 256, 0, stream>>>(yh, h, cols, nnz, wv, lib);
  k_p2fin <<<2000, 256, 0, stream>>>(lib, h, cols, nnz, wv, W2, b2, out);
}

// Round 5
// 437.527 us; speedup vs baseline: 1.0834x; 1.0662x over previous
//
#include <hip/hip_runtime.h>
#include <math.h>

#define NROW   8000
#define NFEATD 512
#define NHID   128
#define NCLS   64
#define CAP    64
#define EPSV   1e-12f
#define ALV    0.1f
#define NTRAIN 500

typedef __attribute__((ext_vector_type(8))) short bf16x8;
typedef __attribute__((ext_vector_type(4))) float f32x4;

__device__ __forceinline__ float wsum(float v) {
#pragma unroll
  for (int off = 32; off > 0; off >>= 1) v += __shfl_xor(v, off, 64);
  return v;
}
__device__ __forceinline__ float wmax(float v) {
#pragma unroll
  for (int off = 32; off > 0; off >>= 1) v = fmaxf(v, __shfl_xor(v, off, 64));
  return v;
}
__device__ __forceinline__ unsigned short f2bf(float f) {   // RTN-even
  unsigned int u = __float_as_uint(f);
  unsigned int r = u + 0x7FFFu + ((u >> 16) & 1u);
  return (unsigned short)(r >> 16);
}
__device__ __forceinline__ unsigned pack4(float4 v) {
  return (unsigned)(v.x != 0.f) | ((unsigned)(v.y != 0.f) << 1) |
         ((unsigned)(v.z != 0.f) << 2) | ((unsigned)(v.w != 0.f) << 3);
}

// ---------------------------------------------------------------------------
// Cast W0 -> bf16 fragment-ordered: w0s[c*4096 + n*32 + k] = bf16(W0[(c*32+k)*128+n])
// 128 KB total, stays L2-hot for all GEMM-role blocks. Grid 64 x 256.
// ---------------------------------------------------------------------------
__global__ __launch_bounds__(256) void k_prep(const float* __restrict__ W0,
                                              unsigned short* __restrict__ w0s) {
  int e = blockIdx.x * 1024 + threadIdx.x;
  for (int i = 0; i < 4; ++i, e += 256) {
    int c = e >> 12, n = (e >> 5) & 127, k = e & 31;
    w0s[e] = f2bf(W0[(size_t)(c * 32 + k) * NHID + n]);
  }
}

// ---------------------------------------------------------------------------
// Fused front-end, block-role partitioned. Grid 8500 x 256.
//   blockIdx % 17 == 16 : GEMM tile (500 x 16 rows): h = relu(x@W0+b0) via
//                         bf16 MFMA; A cast in-register, B frags straight
//                         16B global loads from w0s (L2-hot). No LDS.
//   else                 : adj row scan -> cols/nnz via 32-bit presence
//                         bitmask (1 live VGPR across the prefix chain — no
//                         scratch spill), 8x coalesced float4 loads.
// ---------------------------------------------------------------------------
__global__ __launch_bounds__(256) void k_front(const float* __restrict__ adj,
                                               const float* __restrict__ x,
                                               const unsigned short* __restrict__ w0s,
                                               const float* __restrict__ b0,
                                               float* __restrict__ h,
                                               int* __restrict__ cols,
                                               int* __restrict__ nnz) {
  __shared__ int cnt;
  const int t = threadIdx.x;
  const int lane = t & 63;
  const int g = blockIdx.x / 17;
  const int r = blockIdx.x - g * 17;

  if (r == 16) {
    // ---------------- GEMM role ----------------
    const int w = t >> 6;
    const int m = lane & 15, q = lane >> 4;
    const int row0 = g * 16;
    const int wcol = w * 32;
    const float* ap = x + (size_t)(row0 + m) * NFEATD + q * 8;
    f32x4 acc0 = {0.f, 0.f, 0.f, 0.f}, acc1 = {0.f, 0.f, 0.f, 0.f};

    for (int c = 0; c < 16; ++c) {
      float4 a0 = *(const float4*)(ap + c * 32);
      float4 a1 = *(const float4*)(ap + c * 32 + 4);
      bf16x8 bv0 = *(const bf16x8*)(w0s + c * 4096 + (wcol + m) * 32 + q * 8);
      bf16x8 bv1 = *(const bf16x8*)(w0s + c * 4096 + (wcol + 16 + m) * 32 + q * 8);
      bf16x8 av;
      av[0] = (short)f2bf(a0.x); av[1] = (short)f2bf(a0.y);
      av[2] = (short)f2bf(a0.z); av[3] = (short)f2bf(a0.w);
      av[4] = (short)f2bf(a1.x); av[5] = (short)f2bf(a1.y);
      av[6] = (short)f2bf(a1.z); av[7] = (short)f2bf(a1.w);
      acc0 = __builtin_amdgcn_mfma_f32_16x16x32_bf16(av, bv0, acc0, 0, 0, 0);
      acc1 = __builtin_amdgcn_mfma_f32_16x16x32_bf16(av, bv1, acc1, 0, 0, 0);
    }
    const float bc0 = b0[wcol + m], bc1 = b0[wcol + 16 + m];
#pragma unroll
    for (int reg = 0; reg < 4; ++reg) {
      int rr = row0 + q * 4 + reg;
      h[(size_t)rr * NHID + wcol + m] = fmaxf(acc0[reg] + bc0, 0.f);
      h[(size_t)rr * NHID + wcol + 16 + m] = fmaxf(acc1[reg] + bc1, 0.f);
    }
  } else {
    // ---------------- CSR role (bitmask, BW-bound) ----------------
    const int row = g * 16 + r;
    if (t == 0) cnt = 0;
    const float4* rp = (const float4*)(adj + (size_t)row * NROW);
    const float4 z4 = {0.f, 0.f, 0.f, 0.f};
    float4 v0 = rp[t];
    float4 v1 = rp[t + 256];
    float4 v2 = rp[t + 512];
    float4 v3 = rp[t + 768];
    float4 v4 = rp[t + 1024];
    float4 v5 = rp[t + 1280];
    float4 v6 = rp[t + 1536];
    float4 v7 = (t < 208) ? rp[t + 1792] : z4;   // 2000 float4s per row
    unsigned mask = pack4(v0) | (pack4(v1) << 4) | (pack4(v2) << 8) |
                    (pack4(v3) << 12) | (pack4(v4) << 16) | (pack4(v5) << 20) |
                    (pack4(v6) << 24) | (pack4(v7) << 28);
    int c = __popc(mask);
    int pfx = c;                          // inclusive prefix over the wave
#pragma unroll
    for (int off = 1; off < 64; off <<= 1) {
      int tv = __shfl_up(pfx, off, 64);
      if (lane >= off) pfx += tv;
    }
    __syncthreads();                      // cnt=0 visible
    int base = 0;
    if (lane == 63 && pfx) base = atomicAdd(&cnt, pfx);
    base = __shfl(base, 63, 64);
    int p = base + pfx - c;
    unsigned mm = mask;
    while (mm) {
      int b = __ffs(mm) - 1;
      mm &= mm - 1;
      if (p < CAP) cols[row * CAP + p] = 4 * t + ((b >> 2) << 10) + (b & 3);
      ++p;
    }
    __syncthreads();
    if (t == 0) nnz[row] = cnt > CAP ? CAP : cnt;
  }
}

// ---------------------------------------------------------------------------
// Fused: Pseudo = h@W1 + b1 (+ 0.1*count(row in idx)*y_label[row]) -> outP
// then y_hat = softmax(Pseudo). Grid 2000 x 256, wave per row.
// ---------------------------------------------------------------------------
__global__ __launch_bounds__(256) void k_pseudo(const float* __restrict__ h,
                                                const float* __restrict__ W1,
                                                const float* __restrict__ b1,
                                                const int* __restrict__ idx,
                                                const float* __restrict__ yl,
                                                float* __restrict__ yh,
                                                float* __restrict__ outP) {
  __shared__ float hr[4][NHID];
  __shared__ int ids[NTRAIN];
  const int w = threadIdx.x >> 6, lane = threadIdx.x & 63;
  const int row = blockIdx.x * 4 + w;
  for (int i = threadIdx.x; i < NTRAIN; i += 256) ids[i] = idx[i];
  hr[w][lane] = h[(size_t)row * NHID + lane];
  hr[w][lane + 64] = h[(size_t)row * NHID + 64 + lane];
  __syncthreads();
  float acc = b1[lane];
#pragma unroll 8
  for (int k = 0; k < NHID; ++k) acc += hr[w][k] * W1[k * NCLS + lane];
  int lo = 0, hi = NTRAIN;
  while (lo < hi) { int mid = (lo + hi) >> 1; if (ids[mid] < row) lo = mid + 1; else hi = mid; }
  int lb = lo; hi = NTRAIN;
  while (lo < hi) { int mid = (lo + hi) >> 1; if (ids[mid] <= row) lo = mid + 1; else hi = mid; }
  int count = lo - lb;
  if (count) acc += ALV * (float)count * yl[(size_t)row * NCLS + lane];
  outP[(size_t)row * NCLS + lane] = acc;
  float mx = wmax(acc);
  float e = __expf(acc - mx);
  float s = wsum(e);
  yh[(size_t)row * NCLS + lane] = e / s;
}

// ---------------------------------------------------------------------------
// Fused edge weights + propagation layer 1. Grid 2000 x 256, wave per row.
// ---------------------------------------------------------------------------
__global__ __launch_bounds__(256) void k_ewp1(const float* __restrict__ yh,
                                              const float* __restrict__ h,
                                              const int* __restrict__ cols,
                                              const int* __restrict__ nnz,
                                              float* __restrict__ wv,
                                              float* __restrict__ lib) {
  const int w = threadIdx.x >> 6, lane = threadIdx.x & 63;
  const int row = blockIdx.x * 4 + w;
  (void)w;
  const int ne = nnz[row];
  int jv = 0;
  if (lane < ne) jv = cols[row * CAP + lane];
  const float yi = yh[(size_t)row * NCLS + lane];
  float rs = 0.f, myw = 0.f;
  for (int e = 0; e < ne; ++e) {
    int j = __shfl(jv, e, 64);
    float p = wsum(yi * yh[(size_t)j * NCLS + lane]);
    if (lane == e) myw = p;
    rs += p;
  }
  myw *= 1.f / fmaxf(rs, EPSV);
  if (lane < ne) wv[row * CAP + lane] = myw;
  float a0 = 0.f, a1 = 0.f;
  for (int e = 0; e < ne; ++e) {
    int j = __shfl(jv, e, 64);
    float wt = __shfl(myw, e, 64);
    a0 += wt * h[(size_t)j * NHID + lane];
    a1 += wt * h[(size_t)j * NHID + 64 + lane];
  }
  float v0 = (1.f - ALV) * a0 + ALV * h[(size_t)row * NHID + lane];
  float v1 = (1.f - ALV) * a1 + ALV * h[(size_t)row * NHID + 64 + lane];
  float s = wsum(v0 * v0 + v1 * v1);
  float inv = 1.f / fmaxf(sqrtf(s), EPSV);
  lib[(size_t)row * NHID + lane] = v0 * inv;
  lib[(size_t)row * NHID + 64 + lane] = v1 * inv;
}

// ---------------------------------------------------------------------------
// Fused propagation layer 2 + final head. Grid 2000 x 256, wave per row.
// ---------------------------------------------------------------------------
__global__ __launch_bounds__(256) void k_p2fin(const float* __restrict__ lib,
                                               const float* __restrict__ h,
                                               const int* __restrict__ cols,
                                               const int* __restrict__ nnz,
                                               const float* __restrict__ wv,
                                               const float* __restrict__ W2,
                                               const float* __restrict__ b2,
                                               float* __restrict__ out) {
  __shared__ float lrow[4][NHID];
  const int w = threadIdx.x >> 6, lane = threadIdx.x & 63;
  const int row = blockIdx.x * 4 + w;
  const int ne = nnz[row];
  int jv = 0; float wt = 0.f;
  if (lane < ne) { jv = cols[row * CAP + lane]; wt = wv[row * CAP + lane]; }
  float a0 = 0.f, a1 = 0.f;
  for (int e = 0; e < ne; ++e) {
    int j = __shfl(jv, e, 64);
    float we = __shfl(wt, e, 64);
    a0 += we * lib[(size_t)j * NHID + lane];
    a1 += we * lib[(size_t)j * NHID + 64 + lane];
  }
  float v0 = (1.f - ALV) * a0 + ALV * h[(size_t)row * NHID + lane];
  float v1 = (1.f - ALV) * a1 + ALV * h[(size_t)row * NHID + 64 + lane];
  float s = wsum(v0 * v0 + v1 * v1);
  float inv = 1.f / fmaxf(sqrtf(s), EPSV);
  lrow[w][lane] = v0 * inv;
  lrow[w][lane + 64] = v1 * inv;
  __syncthreads();
  float acc = b2[lane];
#pragma unroll 8
  for (int k = 0; k < NHID; ++k) acc += lrow[w][k] * W2[k * NCLS + lane];
  float mx = wmax(acc);
  float l = acc - mx;
  float se = wsum(__expf(l));
  out[(size_t)row * NCLS + lane] = l - __logf(se);
}

// ---------------------------------------------------------------------------
extern "C" void kernel_launch(void* const* d_in, const int* in_sizes, int n_in,
                              void* d_out, int out_size, void* d_ws, size_t ws_size,
                              hipStream_t stream) {
  const float* x   = (const float*)d_in[0];
  const float* adj = (const float*)d_in[1];
  const float* yl  = (const float*)d_in[2];
  const int*   idx = (const int*)d_in[3];
  const float* W0  = (const float*)d_in[4];
  const float* b0  = (const float*)d_in[5];
  const float* W1  = (const float*)d_in[6];
  const float* b1  = (const float*)d_in[7];
  const float* W2  = (const float*)d_in[8];
  const float* b2  = (const float*)d_in[9];
  float* out = (float*)d_out;

  char* wsb = (char*)d_ws;
  float* h    = (float*)(wsb);                  // 4,096,000 B
  float* lib  = (float*)(wsb + 4096000);        // 4,096,000 B
  float* yh   = (float*)(wsb + 8192000);        // 2,048,000 B
  float* wv   = (float*)(wsb + 10240000);       // 2,048,000 B
  int*   cols = (int*)(wsb + 12288000);         // 2,048,000 B
  int*   nnz  = (int*)(wsb + 14336000);         //    32,000 B
  unsigned short* w0s = (unsigned short*)(wsb + 14368000);  // 131,072 B

  k_prep  <<<64,   256, 0, stream>>>(W0, w0s);
  k_front <<<8500, 256, 0, stream>>>(adj, x, w0s, b0, h, cols, nnz);
  k_pseudo<<<2000, 256, 0, stream>>>(h, W1, b1, idx, yl, yh, out + 512000);
  k_ewp1  <<<2000, 256, 0, stream>>>(yh, h, cols, nnz, wv, lib);
  k_p2fin <<<2000, 256, 0, stream>>>(lib, h, cols, nnz, wv, W2, b2, out);
}

// Round 6
// 434.324 us; speedup vs baseline: 1.0913x; 1.0074x over previous
//
#include <hip/hip_runtime.h>
#include <math.h>

#define NROW   8000
#define NFEATD 512
#define NHID   128
#define NCLS   64
#define CAP    64
#define EPSV   1e-12f
#define ALV    0.1f
#define NTRAIN 500

typedef __attribute__((ext_vector_type(8))) short bf16x8;
typedef __attribute__((ext_vector_type(4))) float f32x4;

__device__ __forceinline__ float wsum(float v) {
#pragma unroll
  for (int off = 32; off > 0; off >>= 1) v += __shfl_xor(v, off, 64);
  return v;
}
__device__ __forceinline__ float wmax(float v) {
#pragma unroll
  for (int off = 32; off > 0; off >>= 1) v = fmaxf(v, __shfl_xor(v, off, 64));
  return v;
}
__device__ __forceinline__ unsigned short f2bf(float f) {   // RTN-even
  unsigned int u = __float_as_uint(f);
  unsigned int r = u + 0x7FFFu + ((u >> 16) & 1u);
  return (unsigned short)(r >> 16);
}
__device__ __forceinline__ unsigned pack4(float4 v) {
  return (unsigned)(v.x != 0.f) | ((unsigned)(v.y != 0.f) << 1) |
         ((unsigned)(v.z != 0.f) << 2) | ((unsigned)(v.w != 0.f) << 3);
}

// ---------------------------------------------------------------------------
// Cast W0 -> bf16 fragment-ordered: w0s[c*4096 + n*32 + k] = bf16(W0[(c*32+k)*128+n])
// 128 KB total, L2-hot for all GEMM-role blocks. Grid 64 x 256.
// ---------------------------------------------------------------------------
__global__ __launch_bounds__(256) void k_prep(const float* __restrict__ W0,
                                              unsigned short* __restrict__ w0s) {
  int e = blockIdx.x * 1024 + threadIdx.x;
  for (int i = 0; i < 4; ++i, e += 256) {
    int c = e >> 12, n = (e >> 5) & 127, k = e & 31;
    w0s[e] = f2bf(W0[(size_t)(c * 32 + k) * NHID + n]);
  }
}

// ---------------------------------------------------------------------------
// Fused front-end, block-role partitioned. Grid 8500 x 256.
//   blockIdx % 17 == 16 : GEMM tile (500 x 16 rows): h = relu(x@W0+b0) via
//                         bf16 MFMA, THEN Pseudo = h@W1+b1 (+injection) and
//                         y_hat = softmax(Pseudo) for the same 16 rows,
//                         reading the h-tile from LDS. Kills k_pseudo.
//   else                 : adj row scan -> cols/nnz via 32-bit presence
//                         bitmask (no scratch spill), 8x coalesced float4.
// ---------------------------------------------------------------------------
__global__ __launch_bounds__(256) void k_front(const float* __restrict__ adj,
                                               const float* __restrict__ x,
                                               const unsigned short* __restrict__ w0s,
                                               const float* __restrict__ b0,
                                               const float* __restrict__ W1,
                                               const float* __restrict__ b1,
                                               const int* __restrict__ idx,
                                               const float* __restrict__ yl,
                                               float* __restrict__ h,
                                               float* __restrict__ yh,
                                               float* __restrict__ outP,
                                               int* __restrict__ cols,
                                               int* __restrict__ nnz) {
  __shared__ float hs[16][NHID];   // GEMM role: h tile (8 KB)
  __shared__ int ids[NTRAIN];      // GEMM role: sorted train ids (2 KB)
  __shared__ int cnt;              // CSR role
  const int t = threadIdx.x;
  const int lane = t & 63;
  const int g = blockIdx.x / 17;
  const int r = blockIdx.x - g * 17;

  if (r == 16) {
    // ---------------- GEMM + pseudo/softmax role ----------------
    const int w = t >> 6;
    const int m = lane & 15, q = lane >> 4;
    const int row0 = g * 16;
    const int wcol = w * 32;
    for (int i = t; i < NTRAIN; i += 256) ids[i] = idx[i];
    const float* ap = x + (size_t)(row0 + m) * NFEATD + q * 8;
    f32x4 acc0 = {0.f, 0.f, 0.f, 0.f}, acc1 = {0.f, 0.f, 0.f, 0.f};

    for (int c = 0; c < 16; ++c) {
      float4 a0 = *(const float4*)(ap + c * 32);
      float4 a1 = *(const float4*)(ap + c * 32 + 4);
      bf16x8 bv0 = *(const bf16x8*)(w0s + c * 4096 + (wcol + m) * 32 + q * 8);
      bf16x8 bv1 = *(const bf16x8*)(w0s + c * 4096 + (wcol + 16 + m) * 32 + q * 8);
      bf16x8 av;
      av[0] = (short)f2bf(a0.x); av[1] = (short)f2bf(a0.y);
      av[2] = (short)f2bf(a0.z); av[3] = (short)f2bf(a0.w);
      av[4] = (short)f2bf(a1.x); av[5] = (short)f2bf(a1.y);
      av[6] = (short)f2bf(a1.z); av[7] = (short)f2bf(a1.w);
      acc0 = __builtin_amdgcn_mfma_f32_16x16x32_bf16(av, bv0, acc0, 0, 0, 0);
      acc1 = __builtin_amdgcn_mfma_f32_16x16x32_bf16(av, bv1, acc1, 0, 0, 0);
    }
    const float bc0 = b0[wcol + m], bc1 = b0[wcol + 16 + m];
#pragma unroll
    for (int reg = 0; reg < 4; ++reg) {
      int lr = q * 4 + reg;
      float h0v = fmaxf(acc0[reg] + bc0, 0.f);
      float h1v = fmaxf(acc1[reg] + bc1, 0.f);
      h[(size_t)(row0 + lr) * NHID + wcol + m] = h0v;
      h[(size_t)(row0 + lr) * NHID + wcol + 16 + m] = h1v;
      hs[lr][wcol + m] = h0v;
      hs[lr][wcol + 16 + m] = h1v;
    }
    __syncthreads();
    // Pseudo + injection + softmax: wave w handles rows w*4..w*4+3, lane=class
    const float b1v = b1[lane];
#pragma unroll
    for (int rr = 0; rr < 4; ++rr) {
      const int lr = w * 4 + rr;
      const int grow = row0 + lr;
      float acc = b1v;
#pragma unroll 8
      for (int k = 0; k < NHID; ++k) acc += hs[lr][k] * W1[k * NCLS + lane];
      int lo = 0, hi = NTRAIN;
      while (lo < hi) { int mid = (lo + hi) >> 1; if (ids[mid] < grow) lo = mid + 1; else hi = mid; }
      int lb = lo; hi = NTRAIN;
      while (lo < hi) { int mid = (lo + hi) >> 1; if (ids[mid] <= grow) lo = mid + 1; else hi = mid; }
      int count = lo - lb;
      if (count) acc += ALV * (float)count * yl[(size_t)grow * NCLS + lane];
      outP[(size_t)grow * NCLS + lane] = acc;
      float mx = wmax(acc);
      float e = __expf(acc - mx);
      float s = wsum(e);
      yh[(size_t)grow * NCLS + lane] = e / s;
    }
  } else {
    // ---------------- CSR role (bitmask, BW-bound) ----------------
    const int row = g * 16 + r;
    if (t == 0) cnt = 0;
    const float4* rp = (const float4*)(adj + (size_t)row * NROW);
    const float4 z4 = {0.f, 0.f, 0.f, 0.f};
    float4 v0 = rp[t];
    float4 v1 = rp[t + 256];
    float4 v2 = rp[t + 512];
    float4 v3 = rp[t + 768];
    float4 v4 = rp[t + 1024];
    float4 v5 = rp[t + 1280];
    float4 v6 = rp[t + 1536];
    float4 v7 = (t < 208) ? rp[t + 1792] : z4;   // 2000 float4s per row
    unsigned mask = pack4(v0) | (pack4(v1) << 4) | (pack4(v2) << 8) |
                    (pack4(v3) << 12) | (pack4(v4) << 16) | (pack4(v5) << 20) |
                    (pack4(v6) << 24) | (pack4(v7) << 28);
    int c = __popc(mask);
    int pfx = c;                          // inclusive prefix over the wave
#pragma unroll
    for (int off = 1; off < 64; off <<= 1) {
      int tv = __shfl_up(pfx, off, 64);
      if (lane >= off) pfx += tv;
    }
    __syncthreads();                      // cnt=0 visible
    int base = 0;
    if (lane == 63 && pfx) base = atomicAdd(&cnt, pfx);
    base = __shfl(base, 63, 64);
    int p = base + pfx - c;
    unsigned mm = mask;
    while (mm) {
      int b = __ffs(mm) - 1;
      mm &= mm - 1;
      if (p < CAP) cols[row * CAP + p] = 4 * t + ((b >> 2) << 10) + (b & 3);
      ++p;
    }
    __syncthreads();
    if (t == 0) nnz[row] = cnt > CAP ? CAP : cnt;
  }
}

// ---------------------------------------------------------------------------
// Fused edge weights + propagation layer 1. Grid 2000 x 256, wave per row.
// Dot phase: lane e owns edge e's full 64-class dot (parallel, one wsum).
// ---------------------------------------------------------------------------
__global__ __launch_bounds__(256) void k_ewp1(const float* __restrict__ yh,
                                              const float* __restrict__ h,
                                              const int* __restrict__ cols,
                                              const int* __restrict__ nnz,
                                              float* __restrict__ wv,
                                              float* __restrict__ lib) {
  __shared__ float yrow[4][NCLS];
  const int w = threadIdx.x >> 6, lane = threadIdx.x & 63;
  const int row = blockIdx.x * 4 + w;
  const int ne = nnz[row];
  int jv = 0;
  if (lane < ne) jv = cols[row * CAP + lane];
  yrow[w][lane] = yh[(size_t)row * NCLS + lane];
  __syncthreads();
  float dot = 0.f;
  if (lane < ne) {
    const float4* jp = (const float4*)(yh + (size_t)jv * NCLS);
    const float4* rp = (const float4*)yrow[w];
#pragma unroll
    for (int c4 = 0; c4 < NCLS / 4; ++c4) {
      float4 a = rp[c4], b = jp[c4];
      dot += a.x * b.x + a.y * b.y + a.z * b.z + a.w * b.w;
    }
  }
  float rs = wsum(dot);
  float myw = dot * (1.f / fmaxf(rs, EPSV));
  if (lane < ne) wv[row * CAP + lane] = myw;
  float a0 = 0.f, a1 = 0.f;
  for (int e = 0; e < ne; ++e) {
    int j = __shfl(jv, e, 64);
    float wt = __shfl(myw, e, 64);
    a0 += wt * h[(size_t)j * NHID + lane];
    a1 += wt * h[(size_t)j * NHID + 64 + lane];
  }
  float v0 = (1.f - ALV) * a0 + ALV * h[(size_t)row * NHID + lane];
  float v1 = (1.f - ALV) * a1 + ALV * h[(size_t)row * NHID + 64 + lane];
  float s = wsum(v0 * v0 + v1 * v1);
  float inv = 1.f / fmaxf(sqrtf(s), EPSV);
  lib[(size_t)row * NHID + lane] = v0 * inv;
  lib[(size_t)row * NHID + 64 + lane] = v1 * inv;
}

// ---------------------------------------------------------------------------
// Fused propagation layer 2 + final head. Grid 2000 x 256, wave per row.
// ---------------------------------------------------------------------------
__global__ __launch_bounds__(256) void k_p2fin(const float* __restrict__ lib,
                                               const float* __restrict__ h,
                                               const int* __restrict__ cols,
                                               const int* __restrict__ nnz,
                                               const float* __restrict__ wv,
                                               const float* __restrict__ W2,
                                               const float* __restrict__ b2,
                                               float* __restrict__ out) {
  __shared__ float lrow[4][NHID];
  const int w = threadIdx.x >> 6, lane = threadIdx.x & 63;
  const int row = blockIdx.x * 4 + w;
  const int ne = nnz[row];
  int jv = 0; float wt = 0.f;
  if (lane < ne) { jv = cols[row * CAP + lane]; wt = wv[row * CAP + lane]; }
  float a0 = 0.f, a1 = 0.f;
  for (int e = 0; e < ne; ++e) {
    int j = __shfl(jv, e, 64);
    float we = __shfl(wt, e, 64);
    a0 += we * lib[(size_t)j * NHID + lane];
    a1 += we * lib[(size_t)j * NHID + 64 + lane];
  }
  float v0 = (1.f - ALV) * a0 + ALV * h[(size_t)row * NHID + lane];
  float v1 = (1.f - ALV) * a1 + ALV * h[(size_t)row * NHID + 64 + lane];
  float s = wsum(v0 * v0 + v1 * v1);
  float inv = 1.f / fmaxf(sqrtf(s), EPSV);
  lrow[w][lane] = v0 * inv;
  lrow[w][lane + 64] = v1 * inv;
  __syncthreads();
  float acc = b2[lane];
#pragma unroll 8
  for (int k = 0; k < NHID; ++k) acc += lrow[w][k] * W2[k * NCLS + lane];
  float mx = wmax(acc);
  float l = acc - mx;
  float se = wsum(__expf(l));
  out[(size_t)row * NCLS + lane] = l - __logf(se);
}

// ---------------------------------------------------------------------------
extern "C" void kernel_launch(void* const* d_in, const int* in_sizes, int n_in,
                              void* d_out, int out_size, void* d_ws, size_t ws_size,
                              hipStream_t stream) {
  const float* x   = (const float*)d_in[0];
  const float* adj = (const float*)d_in[1];
  const float* yl  = (const float*)d_in[2];
  const int*   idx = (const int*)d_in[3];
  const float* W0  = (const float*)d_in[4];
  const float* b0  = (const float*)d_in[5];
  const float* W1  = (const float*)d_in[6];
  const float* b1  = (const float*)d_in[7];
  const float* W2  = (const float*)d_in[8];
  const float* b2  = (const float*)d_in[9];
  float* out = (float*)d_out;

  char* wsb = (char*)d_ws;
  float* h    = (float*)(wsb);                  // 4,096,000 B
  float* lib  = (float*)(wsb + 4096000);        // 4,096,000 B
  float* yh   = (float*)(wsb + 8192000);        // 2,048,000 B
  float* wv   = (float*)(wsb + 10240000);       // 2,048,000 B
  int*   cols = (int*)(wsb + 12288000);         // 2,048,000 B
  int*   nnz  = (int*)(wsb + 14336000);         //    32,000 B
  unsigned short* w0s = (unsigned short*)(wsb + 14368000);  // 131,072 B

  k_prep  <<<64,   256, 0, stream>>>(W0, w0s);
  k_front <<<8500, 256, 0, stream>>>(adj, x, w0s, b0, W1, b1, idx, yl,
                                     h, yh, out + 512000, cols, nnz);
  k_ewp1  <<<2000, 256, 0, stream>>>(yh, h, cols, nnz, wv, lib);
  k_p2fin <<<2000, 256, 0, stream>>>(lib, h, cols, nnz, wv, W2, b2, out);
}

// Round 7
// 419.473 us; speedup vs baseline: 1.1300x; 1.0354x over previous
//
#include <hip/hip_runtime.h>
#include <math.h>

#define NROW   8000
#define NFEATD 512
#define NHID   128
#define NCLS   64
#define CAP    64
#define EPSV   1e-12f
#define ALV    0.1f
#define NTRAIN 500

typedef __attribute__((ext_vector_type(8))) short bf16x8;
typedef __attribute__((ext_vector_type(4))) float f32x4;

__device__ __forceinline__ float wsum(float v) {
#pragma unroll
  for (int off = 32; off > 0; off >>= 1) v += __shfl_xor(v, off, 64);
  return v;
}
__device__ __forceinline__ float wmax(float v) {
#pragma unroll
  for (int off = 32; off > 0; off >>= 1) v = fmaxf(v, __shfl_xor(v, off, 64));
  return v;
}
__device__ __forceinline__ unsigned short f2bf(float f) {   // RTN-even
  unsigned int u = __float_as_uint(f);
  unsigned int r = u + 0x7FFFu + ((u >> 16) & 1u);
  return (unsigned short)(r >> 16);
}

// ---------------------------------------------------------------------------
// Prep: cast W0 -> bf16 fragment-ordered w0s (128 KB, L2-hot) AND zero the
// per-row edge counters (ws is poisoned 0xAA every iteration). Grid 64 x 256.
// ---------------------------------------------------------------------------
__global__ __launch_bounds__(256) void k_prep(const float* __restrict__ W0,
                                              unsigned short* __restrict__ w0s,
                                              int* __restrict__ gcnt) {
  int e = blockIdx.x * 1024 + threadIdx.x;
  for (int i = 0; i < 4; ++i, e += 256) {
    int c = e >> 12, n = (e >> 5) & 127, k = e & 31;
    w0s[e] = f2bf(W0[(size_t)(c * 32 + k) * NHID + n]);
  }
  int z = blockIdx.x * 256 + threadIdx.x;
  if (z < NROW) gcnt[z] = 0;
}

// ---------------------------------------------------------------------------
// Fused front-end, block-role partitioned. Grid 8500 x 256.
//   blockIdx % 17 == 16 : GEMM tile (500 x 16 rows): h = relu(x@W0+b0) via
//                         bf16 MFMA; then Pseudo = h@W1+b1 (+injection) and
//                         y_hat = softmax(Pseudo) for the same rows from LDS.
//   else                 : adj row scan -> cols/gcnt. BARRIER-FREE: 8
//                         nontemporal float4 loads in flight; each (rare)
//                         nonzero claims a slot via global atomicAdd. No LDS,
//                         no prefix chain, no __syncthreads in this role.
// ---------------------------------------------------------------------------
__global__ __launch_bounds__(256) void k_front(const float* __restrict__ adj,
                                               const float* __restrict__ x,
                                               const unsigned short* __restrict__ w0s,
                                               const float* __restrict__ b0,
                                               const float* __restrict__ W1,
                                               const float* __restrict__ b1,
                                               const int* __restrict__ idx,
                                               const float* __restrict__ yl,
                                               float* __restrict__ h,
                                               float* __restrict__ yh,
                                               float* __restrict__ outP,
                                               int* __restrict__ cols,
                                               int* __restrict__ gcnt) {
  __shared__ float hs[16][NHID];   // GEMM role only (8 KB)
  __shared__ int ids[NTRAIN];      // GEMM role only (2 KB)
  const int t = threadIdx.x;
  const int lane = t & 63;
  const int g = blockIdx.x / 17;
  const int r = blockIdx.x - g * 17;

  if (r == 16) {
    // ---------------- GEMM + pseudo/softmax role ----------------
    const int w = t >> 6;
    const int m = lane & 15, q = lane >> 4;
    const int row0 = g * 16;
    const int wcol = w * 32;
    for (int i = t; i < NTRAIN; i += 256) ids[i] = idx[i];
    const float* ap = x + (size_t)(row0 + m) * NFEATD + q * 8;
    f32x4 acc0 = {0.f, 0.f, 0.f, 0.f}, acc1 = {0.f, 0.f, 0.f, 0.f};

    for (int c = 0; c < 16; ++c) {
      float4 a0 = *(const float4*)(ap + c * 32);
      float4 a1 = *(const float4*)(ap + c * 32 + 4);
      bf16x8 bv0 = *(const bf16x8*)(w0s + c * 4096 + (wcol + m) * 32 + q * 8);
      bf16x8 bv1 = *(const bf16x8*)(w0s + c * 4096 + (wcol + 16 + m) * 32 + q * 8);
      bf16x8 av;
      av[0] = (short)f2bf(a0.x); av[1] = (short)f2bf(a0.y);
      av[2] = (short)f2bf(a0.z); av[3] = (short)f2bf(a0.w);
      av[4] = (short)f2bf(a1.x); av[5] = (short)f2bf(a1.y);
      av[6] = (short)f2bf(a1.z); av[7] = (short)f2bf(a1.w);
      acc0 = __builtin_amdgcn_mfma_f32_16x16x32_bf16(av, bv0, acc0, 0, 0, 0);
      acc1 = __builtin_amdgcn_mfma_f32_16x16x32_bf16(av, bv1, acc1, 0, 0, 0);
    }
    const float bc0 = b0[wcol + m], bc1 = b0[wcol + 16 + m];
#pragma unroll
    for (int reg = 0; reg < 4; ++reg) {
      int lr = q * 4 + reg;
      float h0v = fmaxf(acc0[reg] + bc0, 0.f);
      float h1v = fmaxf(acc1[reg] + bc1, 0.f);
      h[(size_t)(row0 + lr) * NHID + wcol + m] = h0v;
      h[(size_t)(row0 + lr) * NHID + wcol + 16 + m] = h1v;
      hs[lr][wcol + m] = h0v;
      hs[lr][wcol + 16 + m] = h1v;
    }
    __syncthreads();
    const float b1v = b1[lane];
#pragma unroll
    for (int rr = 0; rr < 4; ++rr) {
      const int lr = w * 4 + rr;
      const int grow = row0 + lr;
      float acc = b1v;
#pragma unroll 8
      for (int k = 0; k < NHID; ++k) acc += hs[lr][k] * W1[k * NCLS + lane];
      int lo = 0, hi = NTRAIN;
      while (lo < hi) { int mid = (lo + hi) >> 1; if (ids[mid] < grow) lo = mid + 1; else hi = mid; }
      int lb = lo; hi = NTRAIN;
      while (lo < hi) { int mid = (lo + hi) >> 1; if (ids[mid] <= grow) lo = mid + 1; else hi = mid; }
      int count = lo - lb;
      if (count) acc += ALV * (float)count * yl[(size_t)grow * NCLS + lane];
      outP[(size_t)grow * NCLS + lane] = acc;
      float mx = wmax(acc);
      float e = __expf(acc - mx);
      float s = wsum(e);
      yh[(size_t)grow * NCLS + lane] = e / s;
    }
  } else {
    // ---------------- CSR role (barrier-free, atomic slot claim) ----------
    const int row = g * 16 + r;
    const f32x4* rp = (const f32x4*)(adj + (size_t)row * NROW);
    int* rowcols = cols + row * CAP;
    const f32x4 z4 = {0.f, 0.f, 0.f, 0.f};
    f32x4 v[8];
#pragma unroll
    for (int i = 0; i < 7; ++i) v[i] = __builtin_nontemporal_load(rp + t + (i << 8));
    v[7] = (t < 208) ? __builtin_nontemporal_load(rp + t + 1792) : z4;  // 2000 f32x4/row
#pragma unroll
    for (int i = 0; i < 8; ++i) {
      f32x4 w = v[i];
      if (w[0] != 0.f || w[1] != 0.f || w[2] != 0.f || w[3] != 0.f) {
        int bcol = (t + (i << 8)) << 2;
#pragma unroll
        for (int j = 0; j < 4; ++j) {
          if (w[j] != 0.f) {
            int p = atomicAdd(gcnt + row, 1);
            if (p < CAP) rowcols[p] = bcol + j;
          }
        }
      }
    }
  }
}

// ---------------------------------------------------------------------------
// Fused edge weights + propagation layer 1. Grid 2000 x 256, wave per row.
// Dot phase: lane e owns edge e's full 64-class dot (parallel, one wsum).
// ---------------------------------------------------------------------------
__global__ __launch_bounds__(256) void k_ewp1(const float* __restrict__ yh,
                                              const float* __restrict__ h,
                                              const int* __restrict__ cols,
                                              const int* __restrict__ gcnt,
                                              float* __restrict__ wv,
                                              float* __restrict__ lib) {
  __shared__ float yrow[4][NCLS];
  const int w = threadIdx.x >> 6, lane = threadIdx.x & 63;
  const int row = blockIdx.x * 4 + w;
  const int ne = min(gcnt[row], CAP);
  int jv = 0;
  if (lane < ne) jv = cols[row * CAP + lane];
  yrow[w][lane] = yh[(size_t)row * NCLS + lane];
  __syncthreads();
  float dot = 0.f;
  if (lane < ne) {
    const float4* jp = (const float4*)(yh + (size_t)jv * NCLS);
    const float4* rp = (const float4*)yrow[w];
#pragma unroll
    for (int c4 = 0; c4 < NCLS / 4; ++c4) {
      float4 a = rp[c4], b = jp[c4];
      dot += a.x * b.x + a.y * b.y + a.z * b.z + a.w * b.w;
    }
  }
  float rs = wsum(dot);
  float myw = dot * (1.f / fmaxf(rs, EPSV));
  if (lane < ne) wv[row * CAP + lane] = myw;
  float a0 = 0.f, a1 = 0.f;
  for (int e = 0; e < ne; ++e) {
    int j = __shfl(jv, e, 64);
    float wt = __shfl(myw, e, 64);
    a0 += wt * h[(size_t)j * NHID + lane];
    a1 += wt * h[(size_t)j * NHID + 64 + lane];
  }
  float v0 = (1.f - ALV) * a0 + ALV * h[(size_t)row * NHID + lane];
  float v1 = (1.f - ALV) * a1 + ALV * h[(size_t)row * NHID + 64 + lane];
  float s = wsum(v0 * v0 + v1 * v1);
  float inv = 1.f / fmaxf(sqrtf(s), EPSV);
  lib[(size_t)row * NHID + lane] = v0 * inv;
  lib[(size_t)row * NHID + 64 + lane] = v1 * inv;
}

// ---------------------------------------------------------------------------
// Fused propagation layer 2 + final head. Grid 2000 x 256, wave per row.
// ---------------------------------------------------------------------------
__global__ __launch_bounds__(256) void k_p2fin(const float* __restrict__ lib,
                                               const float* __restrict__ h,
                                               const int* __restrict__ cols,
                                               const int* __restrict__ gcnt,
                                               const float* __restrict__ wv,
                                               const float* __restrict__ W2,
                                               const float* __restrict__ b2,
                                               float* __restrict__ out) {
  __shared__ float lrow[4][NHID];
  const int w = threadIdx.x >> 6, lane = threadIdx.x & 63;
  const int row = blockIdx.x * 4 + w;
  const int ne = min(gcnt[row], CAP);
  int jv = 0; float wt = 0.f;
  if (lane < ne) { jv = cols[row * CAP + lane]; wt = wv[row * CAP + lane]; }
  float a0 = 0.f, a1 = 0.f;
  for (int e = 0; e < ne; ++e) {
    int j = __shfl(jv, e, 64);
    float we = __shfl(wt, e, 64);
    a0 += we * lib[(size_t)j * NHID + lane];
    a1 += we * lib[(size_t)j * NHID + 64 + lane];
  }
  float v0 = (1.f - ALV) * a0 + ALV * h[(size_t)row * NHID + lane];
  float v1 = (1.f - ALV) * a1 + ALV * h[(size_t)row * NHID + 64 + lane];
  float s = wsum(v0 * v0 + v1 * v1);
  float inv = 1.f / fmaxf(sqrtf(s), EPSV);
  lrow[w][lane] = v0 * inv;
  lrow[w][lane + 64] = v1 * inv;
  __syncthreads();
  float acc = b2[lane];
#pragma unroll 8
  for (int k = 0; k < NHID; ++k) acc += lrow[w][k] * W2[k * NCLS + lane];
  float mx = wmax(acc);
  float l = acc - mx;
  float se = wsum(__expf(l));
  out[(size_t)row * NCLS + lane] = l - __logf(se);
}

// ---------------------------------------------------------------------------
extern "C" void kernel_launch(void* const* d_in, const int* in_sizes, int n_in,
                              void* d_out, int out_size, void* d_ws, size_t ws_size,
                              hipStream_t stream) {
  const float* x   = (const float*)d_in[0];
  const float* adj = (const float*)d_in[1];
  const float* yl  = (const float*)d_in[2];
  const int*   idx = (const int*)d_in[3];
  const float* W0  = (const float*)d_in[4];
  const float* b0  = (const float*)d_in[5];
  const float* W1  = (const float*)d_in[6];
  const float* b1  = (const float*)d_in[7];
  const float* W2  = (const float*)d_in[8];
  const float* b2  = (const float*)d_in[9];
  float* out = (float*)d_out;

  char* wsb = (char*)d_ws;
  float* h    = (float*)(wsb);                  // 4,096,000 B
  float* lib  = (float*)(wsb + 4096000);        // 4,096,000 B
  float* yh   = (float*)(wsb + 8192000);        // 2,048,000 B
  float* wv   = (float*)(wsb + 10240000);       // 2,048,000 B
  int*   cols = (int*)(wsb + 12288000);         // 2,048,000 B
  int*   gcnt = (int*)(wsb + 14336000);         //    32,000 B
  unsigned short* w0s = (unsigned short*)(wsb + 14368000);  // 131,072 B

  k_prep  <<<64,   256, 0, stream>>>(W0, w0s, gcnt);
  k_front <<<8500, 256, 0, stream>>>(adj, x, w0s, b0, W1, b1, idx, yl,
                                     h, yh, out + 512000, cols, gcnt);
  k_ewp1  <<<2000, 256, 0, stream>>>(yh, h, cols, gcnt, wv, lib);
  k_p2fin <<<2000, 256, 0, stream>>>(lib, h, cols, gcnt, wv, W2, b2, out);
}